// Round 1
// baseline (1746.100 us; speedup 1.0000x reference)
//
#include <hip/hip_runtime.h>
#include <hip/hip_bf16.h>
#include <math.h>

// Problem constants
#define NCLS 64
#define TDIM 128   // CDF_DIM
#define EMB  1024
#define NBATCH 16

// Tile config
#define BM 128
#define BN 128
#define BK 32

typedef __attribute__((ext_vector_type(8))) short bfrag8;   // 8 bf16 (4 VGPRs)
typedef __attribute__((ext_vector_type(4))) float ffrag4;   // 4 fp32 acc

// fp32 -> packed 2x bf16 (RNE via hip header; maps to cvt_pk when available)
__device__ __forceinline__ unsigned int pk2(float lo, float hi) {
    union { __hip_bfloat162 h; unsigned int u; } cv;
    cv.h = __float22bfloat162_rn(make_float2(lo, hi));
    return cv.u;
}

union S8 { bfrag8 s; unsigned int u[4]; };

// out[b*8192 + c*128 + t] = b2[c]
__global__ __launch_bounds__(256) void init_out(const float* __restrict__ b2,
                                                float* __restrict__ out) {
    int i = blockIdx.x * 256 + threadIdx.x;       // 0 .. 131071
    int c = (i >> 7) & (NCLS - 1);
    out[i] = b2[c];
}

// grid: 64 classes * 16 m-blocks * 8 n-blocks. 256 threads (4 waves).
// Each block: C-tile [128 x 128] of h for one class, fused GELU*W2 reduce -> atomicAdd.
__global__ __launch_bounds__(256) void mlp_head_kernel(
    const float* __restrict__ x,  const float* __restrict__ W1,
    const float* __restrict__ b1, const float* __restrict__ W2,
    float* __restrict__ out)
{
    const int bid = blockIdx.x;
    const int nb = bid & 7;           // n-block (8)
    const int mb = (bid >> 3) & 15;   // m-block (16) == batch index b
    const int c  = bid >> 7;          // class

    // frag-major LDS: [tile16 (8)][quad (4)][lane&15 (16)][8 bf16]
    // tile stride 512 shorts, quad stride 128, lane stride 8
    __shared__ __align__(16) short lds_a[BM * BK];
    __shared__ __align__(16) short lds_b[BN * BK];

    const int tid  = threadIdx.x;
    const int lane = tid & 63;
    const int wave = tid >> 6;        // 0..3
    const int wm = wave >> 1, wn = wave & 1;
    const int quad = lane >> 4, l16 = lane & 15;

    // ---- A staging: row = tid&127 (== t), khalf = tid>>7 ----
    const int arow = tid & 127;
    const int akh  = tid >> 7;        // 0/1 -> k offset 16*akh
    const float* aptr = x + ((size_t)mb * 8192 + (size_t)c * 128 + arow) * 1024 + akh * 16;
    short* aw0 = lds_a + (arow >> 4) * 512 + (akh * 2) * 128 + (arow & 15) * 8;
    short* aw1 = aw0 + 128;

    // ---- B staging: n col = tid&127, khalf = tid>>7; 16 scalar k-column loads ----
    const int ncol = tid & 127;
    const int bkh  = tid >> 7;
    const float* bptr = W1 + (size_t)c * 1024 * 1024 + (size_t)(bkh * 16) * 1024
                           + (size_t)nb * 128 + ncol;
    short* bw0 = lds_b + (ncol >> 4) * 512 + (bkh * 2) * 128 + (ncol & 15) * 8;
    short* bw1 = bw0 + 128;

    // ---- fragment read bases ----
    const short* ard = lds_a + (wm * 4) * 512 + quad * 128 + l16 * 8;
    const short* brd = lds_b + (wn * 4) * 512 + quad * 128 + l16 * 8;

    ffrag4 acc[4][4] = {};

    for (int kt = 0; kt < EMB / BK; ++kt) {
        // global loads (fp32)
        float4 a0 = *(const float4*)(aptr + 0);
        float4 a1 = *(const float4*)(aptr + 4);
        float4 a2 = *(const float4*)(aptr + 8);
        float4 a3 = *(const float4*)(aptr + 12);
        float bv[16];
#pragma unroll
        for (int j = 0; j < 16; ++j) bv[j] = bptr[(size_t)j * 1024];
        aptr += BK;
        bptr += (size_t)BK * 1024;

        __syncthreads();   // previous tile's frag reads done

        S8 pa0, pa1, pb0, pb1;
        pa0.u[0] = pk2(a0.x, a0.y); pa0.u[1] = pk2(a0.z, a0.w);
        pa0.u[2] = pk2(a1.x, a1.y); pa0.u[3] = pk2(a1.z, a1.w);
        pa1.u[0] = pk2(a2.x, a2.y); pa1.u[1] = pk2(a2.z, a2.w);
        pa1.u[2] = pk2(a3.x, a3.y); pa1.u[3] = pk2(a3.z, a3.w);
#pragma unroll
        for (int j = 0; j < 4; ++j) pb0.u[j] = pk2(bv[2 * j], bv[2 * j + 1]);
#pragma unroll
        for (int j = 0; j < 4; ++j) pb1.u[j] = pk2(bv[8 + 2 * j], bv[9 + 2 * j]);

        *(bfrag8*)aw0 = pa0.s;
        *(bfrag8*)aw1 = pa1.s;
        *(bfrag8*)bw0 = pb0.s;
        *(bfrag8*)bw1 = pb1.s;

        __syncthreads();   // tile visible

        bfrag8 af[4], bf[4];
#pragma unroll
        for (int mi = 0; mi < 4; ++mi) af[mi] = *(const bfrag8*)(ard + mi * 512);
#pragma unroll
        for (int ni = 0; ni < 4; ++ni) bf[ni] = *(const bfrag8*)(brd + ni * 512);
#pragma unroll
        for (int mi = 0; mi < 4; ++mi)
#pragma unroll
            for (int ni = 0; ni < 4; ++ni)
                acc[mi][ni] = __builtin_amdgcn_mfma_f32_16x16x32_bf16(
                    af[mi], bf[ni], acc[mi][ni], 0, 0, 0);
    }

    // ---- epilogue: out[m] += sum_n gelu(h + b1[n]) * W2[n] ----
    const int nbase = c * 1024 + nb * 128 + wn * 64 + l16;
    float b1v[4], w2v[4];
#pragma unroll
    for (int ni = 0; ni < 4; ++ni) {
        b1v[ni] = b1[nbase + ni * 16];
        w2v[ni] = W2[nbase + ni * 16];
    }

    float* outp = out + (size_t)mb * 8192 + c * 128 + wm * 64 + quad * 4;
#pragma unroll
    for (int mi = 0; mi < 4; ++mi) {
        float s[4] = {0.f, 0.f, 0.f, 0.f};
#pragma unroll
        for (int ni = 0; ni < 4; ++ni) {
#pragma unroll
            for (int r = 0; r < 4; ++r) {
                float h = acc[mi][ni][r] + b1v[ni];
                float g = 0.5f * h * (1.0f + erff(h * 0.70710678118654752f));
                s[r] += g * w2v[ni];
            }
        }
#pragma unroll
        for (int r = 0; r < 4; ++r) {
            // reduce over the 16 cols held by this quad's 16 lanes
            s[r] += __shfl_xor(s[r], 8, 64);
            s[r] += __shfl_xor(s[r], 4, 64);
            s[r] += __shfl_xor(s[r], 2, 64);
            s[r] += __shfl_xor(s[r], 1, 64);
            if (l16 == 0) atomicAdd(outp + mi * 16 + r, s[r]);
        }
    }
}

extern "C" void kernel_launch(void* const* d_in, const int* in_sizes, int n_in,
                              void* d_out, int out_size, void* d_ws, size_t ws_size,
                              hipStream_t stream) {
    const float* x  = (const float*)d_in[0];
    const float* W1 = (const float*)d_in[1];
    const float* b1 = (const float*)d_in[2];
    const float* W2 = (const float*)d_in[3];
    const float* b2 = (const float*)d_in[4];
    float* out = (float*)d_out;

    init_out<<<dim3(512), dim3(256), 0, stream>>>(b2, out);
    mlp_head_kernel<<<dim3(NCLS * 16 * 8), dim3(256), 0, stream>>>(x, W1, b1, W2, out);
}

// Round 2
// 1617.220 us; speedup vs baseline: 1.0797x; 1.0797x over previous
//
#include <hip/hip_runtime.h>
#include <hip/hip_bf16.h>
#include <math.h>

// Problem constants
#define NCLS 64
#define TDIM 128   // CDF_DIM
#define EMB  1024
#define NBATCH 16

// Tile config
#define BM 128
#define BN 128
#define BK 32

typedef __attribute__((ext_vector_type(8))) short bfrag8;   // 8 bf16 (4 VGPRs)
typedef __attribute__((ext_vector_type(4))) float ffrag4;   // 4 fp32 acc

// fp32 -> packed 2x bf16 (RNE)
__device__ __forceinline__ unsigned int pk2(float lo, float hi) {
    union { __hip_bfloat162 h; unsigned int u; } cv;
    cv.h = __float22bfloat162_rn(make_float2(lo, hi));
    return cv.u;
}
__device__ __forceinline__ short f2bs(float f) {
    return (short)(pk2(f, 0.f) & 0xffff);
}

union S8 { bfrag8 s; unsigned int u[4]; };

// async 16B global -> LDS (wave-uniform LDS base + lane*16 is the HW dest rule)
__device__ __forceinline__ void async16(const short* g, const short* l) {
    __builtin_amdgcn_global_load_lds(
        (const __attribute__((address_space(1))) unsigned int*)(unsigned long long)(uintptr_t)g,
        (__attribute__((address_space(3))) unsigned int*)(unsigned int)(uintptr_t)l,
        16, 0, 0);
}

// out[b*8192 + c*128 + t] = b2[c]
__global__ __launch_bounds__(256) void init_out(const float* __restrict__ b2,
                                                float* __restrict__ out) {
    int i = blockIdx.x * 256 + threadIdx.x;       // 0 .. 131071
    int c = (i >> 7) & (NCLS - 1);
    out[i] = b2[c];
}

// x fp32 [131072*1024] -> bf16 same layout. 8 elements/thread.
__global__ __launch_bounds__(256) void cvt_x(const float* __restrict__ x,
                                             short* __restrict__ xb) {
    size_t i = ((size_t)blockIdx.x * 256 + threadIdx.x) * 8;
    float4 a = *(const float4*)(x + i);
    float4 b = *(const float4*)(x + i + 4);
    S8 p;
    p.u[0] = pk2(a.x, a.y); p.u[1] = pk2(a.z, a.w);
    p.u[2] = pk2(b.x, b.y); p.u[3] = pk2(b.z, b.w);
    *(bfrag8*)(xb + i) = p.s;
}

// W1 fp32 [c][k][n] -> W1T bf16 [c][n][k]. 64x64 tile per block via LDS.
__global__ __launch_bounds__(256) void cvt_w1t(const float* __restrict__ W1,
                                               short* __restrict__ w1t) {
    const int bid = blockIdx.x;
    const int nt = bid & 15, kt = (bid >> 4) & 15, c = bid >> 8;
    const int t = threadIdx.x;
    __shared__ short ldsT[64 * 72];   // [n][k], row stride 72 shorts (144B, 16B-aligned)

    const float* src = W1 + (size_t)c * 1048576 + (size_t)(kt * 64) * 1024 + nt * 64;
    const int kr = t >> 4, nq = (t & 15) * 4;
#pragma unroll
    for (int i = 0; i < 4; ++i) {
        int k = kr + i * 16;
        float4 v = *(const float4*)(src + (size_t)k * 1024 + nq);
        ldsT[(nq + 0) * 72 + k] = f2bs(v.x);
        ldsT[(nq + 1) * 72 + k] = f2bs(v.y);
        ldsT[(nq + 2) * 72 + k] = f2bs(v.z);
        ldsT[(nq + 3) * 72 + k] = f2bs(v.w);
    }
    __syncthreads();
    short* dst = w1t + (size_t)c * 1048576 + (size_t)(nt * 64) * 1024 + kt * 64;
#pragma unroll
    for (int p = 0; p < 2; ++p) {
        int chunk = t + p * 256;         // 512 chunks of 8 shorts
        int n = chunk >> 3, kc = chunk & 7;
        bfrag8 v = *(const bfrag8*)(ldsT + n * 72 + kc * 8);
        *(bfrag8*)(dst + (size_t)n * 1024 + kc * 8) = v;
    }
}

// ---------------- fast path: m97-style bf16 GEMM + fused GELU/W2 epilogue --------
// grid: 64 classes * 16 m-blocks * 8 n-blocks, 256 threads (4 waves).
__global__ __launch_bounds__(256) void mlp_gemm(
    const short* __restrict__ xb, const short* __restrict__ w1t,
    const float* __restrict__ b1, const float* __restrict__ W2,
    float* __restrict__ out)
{
    const int bid = blockIdx.x;
    const int nb = bid & 7;
    const int mb = (bid >> 3) & 15;   // batch index
    const int c  = bid >> 7;

    // frag-major LDS: [tile16 (8)][quad (4)][l16 (16)][8 bf16]; tile = 512 shorts
    __shared__ __align__(16) short lds_a[BM * BK];
    __shared__ __align__(16) short lds_b[BN * BK];

    const int tid  = threadIdx.x;
    const int lane = tid & 63;
    const int wave = tid >> 6;        // 0..3
    const int wm = wave >> 1, wn = wave & 1;
    const int quad = lane >> 4, l16 = lane & 15;

    // ---- staging: wave w stages A-tiles {2w,2w+1} and B-tiles {2w,2w+1}.
    // lane l -> (tile, quad=l>>4, l16=l&15): global row tile*16+l16, k-chunk l>>4.
    const short* gA0 = xb + ((size_t)mb * 8192 + c * 128 + (2 * wave) * 16 + l16) * 1024
                          + quad * 8;
    const short* gA1 = gA0 + 16 * 1024;
    const short* gB0 = w1t + (size_t)c * 1048576
                           + (size_t)(nb * 128 + (2 * wave) * 16 + l16) * 1024 + quad * 8;
    const short* gB1 = gB0 + 16 * 1024;
    const short* lA0 = lds_a + (2 * wave) * 512;   // wave-uniform LDS bases
    const short* lA1 = lA0 + 512;
    const short* lB0 = lds_b + (2 * wave) * 512;
    const short* lB1 = lB0 + 512;

    // ---- fragment read bases ----
    const short* ard = lds_a + (wm * 4) * 512 + quad * 128 + l16 * 8;
    const short* brd = lds_b + (wn * 4) * 512 + quad * 128 + l16 * 8;

    ffrag4 acc[4][4] = {};

    for (int kt = 0; kt < EMB / BK; ++kt) {
        __syncthreads();               // prev iter's frag reads done
        async16(gA0, lA0);
        async16(gA1, lA1);
        async16(gB0, lB0);
        async16(gB1, lB1);
        gA0 += BK; gA1 += BK; gB0 += BK; gB1 += BK;
        __syncthreads();               // barrier drains vmcnt -> tile visible

        bfrag8 af[4], bf[4];
#pragma unroll
        for (int mi = 0; mi < 4; ++mi) af[mi] = *(const bfrag8*)(ard + mi * 512);
#pragma unroll
        for (int ni = 0; ni < 4; ++ni) bf[ni] = *(const bfrag8*)(brd + ni * 512);
#pragma unroll
        for (int mi = 0; mi < 4; ++mi)
#pragma unroll
            for (int ni = 0; ni < 4; ++ni)
                acc[mi][ni] = __builtin_amdgcn_mfma_f32_16x16x32_bf16(
                    af[mi], bf[ni], acc[mi][ni], 0, 0, 0);
    }

    // ---- epilogue: out[m] += sum_n gelu(h + b1[n]) * W2[n] ----
    const int nbase = c * 1024 + nb * 128 + wn * 64 + l16;
    float b1v[4], w2v[4];
#pragma unroll
    for (int ni = 0; ni < 4; ++ni) {
        b1v[ni] = b1[nbase + ni * 16];
        w2v[ni] = W2[nbase + ni * 16];
    }

    float* outp = out + (size_t)mb * 8192 + c * 128 + wm * 64 + quad * 4;
#pragma unroll
    for (int mi = 0; mi < 4; ++mi) {
        float s[4] = {0.f, 0.f, 0.f, 0.f};
#pragma unroll
        for (int ni = 0; ni < 4; ++ni) {
#pragma unroll
            for (int r = 0; r < 4; ++r) {
                float h = acc[mi][ni][r] + b1v[ni];
                float g = 0.5f * h * (1.0f + erff(h * 0.70710678118654752f));
                s[r] += g * w2v[ni];
            }
        }
#pragma unroll
        for (int r = 0; r < 4; ++r) {
            s[r] += __shfl_xor(s[r], 8, 64);
            s[r] += __shfl_xor(s[r], 4, 64);
            s[r] += __shfl_xor(s[r], 2, 64);
            s[r] += __shfl_xor(s[r], 1, 64);
            if (l16 == 0) atomicAdd(outp + mi * 16 + r, s[r]);
        }
    }
}

// ---------------- fallback (round-0 kernel, used if ws too small) ----------------
__global__ __launch_bounds__(256) void mlp_head_fallback(
    const float* __restrict__ x,  const float* __restrict__ W1,
    const float* __restrict__ b1, const float* __restrict__ W2,
    float* __restrict__ out)
{
    const int bid = blockIdx.x;
    const int nb = bid & 7;
    const int mb = (bid >> 3) & 15;
    const int c  = bid >> 7;

    __shared__ __align__(16) short lds_a[BM * BK];
    __shared__ __align__(16) short lds_b[BN * BK];

    const int tid  = threadIdx.x;
    const int lane = tid & 63;
    const int wave = tid >> 6;
    const int wm = wave >> 1, wn = wave & 1;
    const int quad = lane >> 4, l16 = lane & 15;

    const int arow = tid & 127;
    const int akh  = tid >> 7;
    const float* aptr = x + ((size_t)mb * 8192 + (size_t)c * 128 + arow) * 1024 + akh * 16;
    short* aw0 = lds_a + (arow >> 4) * 512 + (akh * 2) * 128 + (arow & 15) * 8;
    short* aw1 = aw0 + 128;

    const int ncol = tid & 127;
    const int bkh  = tid >> 7;
    const float* bptr = W1 + (size_t)c * 1024 * 1024 + (size_t)(bkh * 16) * 1024
                           + (size_t)nb * 128 + ncol;
    short* bw0 = lds_b + (ncol >> 4) * 512 + (bkh * 2) * 128 + (ncol & 15) * 8;
    short* bw1 = bw0 + 128;

    const short* ard = lds_a + (wm * 4) * 512 + quad * 128 + l16 * 8;
    const short* brd = lds_b + (wn * 4) * 512 + quad * 128 + l16 * 8;

    ffrag4 acc[4][4] = {};

    for (int kt = 0; kt < EMB / BK; ++kt) {
        float4 a0 = *(const float4*)(aptr + 0);
        float4 a1 = *(const float4*)(aptr + 4);
        float4 a2 = *(const float4*)(aptr + 8);
        float4 a3 = *(const float4*)(aptr + 12);
        float bv[16];
#pragma unroll
        for (int j = 0; j < 16; ++j) bv[j] = bptr[(size_t)j * 1024];
        aptr += BK;
        bptr += (size_t)BK * 1024;

        __syncthreads();

        S8 pa0, pa1, pb0, pb1;
        pa0.u[0] = pk2(a0.x, a0.y); pa0.u[1] = pk2(a0.z, a0.w);
        pa0.u[2] = pk2(a1.x, a1.y); pa0.u[3] = pk2(a1.z, a1.w);
        pa1.u[0] = pk2(a2.x, a2.y); pa1.u[1] = pk2(a2.z, a2.w);
        pa1.u[2] = pk2(a3.x, a3.y); pa1.u[3] = pk2(a3.z, a3.w);
#pragma unroll
        for (int j = 0; j < 4; ++j) pb0.u[j] = pk2(bv[2 * j], bv[2 * j + 1]);
#pragma unroll
        for (int j = 0; j < 4; ++j) pb1.u[j] = pk2(bv[8 + 2 * j], bv[9 + 2 * j]);

        *(bfrag8*)aw0 = pa0.s;
        *(bfrag8*)aw1 = pa1.s;
        *(bfrag8*)bw0 = pb0.s;
        *(bfrag8*)bw1 = pb1.s;

        __syncthreads();

        bfrag8 af[4], bf[4];
#pragma unroll
        for (int mi = 0; mi < 4; ++mi) af[mi] = *(const bfrag8*)(ard + mi * 512);
#pragma unroll
        for (int ni = 0; ni < 4; ++ni) bf[ni] = *(const bfrag8*)(brd + ni * 512);
#pragma unroll
        for (int mi = 0; mi < 4; ++mi)
#pragma unroll
            for (int ni = 0; ni < 4; ++ni)
                acc[mi][ni] = __builtin_amdgcn_mfma_f32_16x16x32_bf16(
                    af[mi], bf[ni], acc[mi][ni], 0, 0, 0);
    }

    const int nbase = c * 1024 + nb * 128 + wn * 64 + l16;
    float b1v[4], w2v[4];
#pragma unroll
    for (int ni = 0; ni < 4; ++ni) {
        b1v[ni] = b1[nbase + ni * 16];
        w2v[ni] = W2[nbase + ni * 16];
    }

    float* outp = out + (size_t)mb * 8192 + c * 128 + wm * 64 + quad * 4;
#pragma unroll
    for (int mi = 0; mi < 4; ++mi) {
        float s[4] = {0.f, 0.f, 0.f, 0.f};
#pragma unroll
        for (int ni = 0; ni < 4; ++ni) {
#pragma unroll
            for (int r = 0; r < 4; ++r) {
                float h = acc[mi][ni][r] + b1v[ni];
                float g = 0.5f * h * (1.0f + erff(h * 0.70710678118654752f));
                s[r] += g * w2v[ni];
            }
        }
#pragma unroll
        for (int r = 0; r < 4; ++r) {
            s[r] += __shfl_xor(s[r], 8, 64);
            s[r] += __shfl_xor(s[r], 4, 64);
            s[r] += __shfl_xor(s[r], 2, 64);
            s[r] += __shfl_xor(s[r], 1, 64);
            if (l16 == 0) atomicAdd(outp + mi * 16 + r, s[r]);
        }
    }
}

extern "C" void kernel_launch(void* const* d_in, const int* in_sizes, int n_in,
                              void* d_out, int out_size, void* d_ws, size_t ws_size,
                              hipStream_t stream) {
    const float* x  = (const float*)d_in[0];
    const float* W1 = (const float*)d_in[1];
    const float* b1 = (const float*)d_in[2];
    const float* W2 = (const float*)d_in[3];
    const float* b2 = (const float*)d_in[4];
    float* out = (float*)d_out;

    const size_t xb_bytes  = (size_t)NBATCH * NCLS * TDIM * EMB * 2;      // 268435456
    const size_t w1t_bytes = (size_t)NCLS * EMB * EMB * 2;                // 134217728

    init_out<<<dim3(512), dim3(256), 0, stream>>>(b2, out);

    if (ws_size >= xb_bytes + w1t_bytes) {
        short* xb  = (short*)d_ws;
        short* w1t = (short*)((char*)d_ws + xb_bytes);
        cvt_x<<<dim3(65536), dim3(256), 0, stream>>>(x, xb);
        cvt_w1t<<<dim3(16384), dim3(256), 0, stream>>>(W1, w1t);
        mlp_gemm<<<dim3(NCLS * 16 * 8), dim3(256), 0, stream>>>(xb, w1t, b1, W2, out);
    } else {
        mlp_head_fallback<<<dim3(NCLS * 16 * 8), dim3(256), 0, stream>>>(x, W1, b1, W2, out);
    }
}